// Round 13
// baseline (210.997 us; speedup 1.0000x reference)
//
#include <hip/hip_runtime.h>
#include <math.h>

#define NP 3136
#define NC 256
#define NB 16
#define HH 56
#define OW 224

typedef float f4 __attribute__((ext_vector_type(4)));  // clang-native for nt load

// ---------------- Stage 1: Mahalanobis distance (R2 core + nt icov + hoist) --
__device__ __forceinline__ void rowstep(const f4 mv, const int c,
                                        const float (&dreg)[4][16], float (&z)[16],
                                        const float (*dc_lds)[20]) {
  float s[16];
#pragma unroll
  for (int b = 0; b < 16; ++b) s[b] = mv[0] * dreg[0][b];
#pragma unroll
  for (int b = 0; b < 16; ++b) s[b] = fmaf(mv[1], dreg[1][b], s[b]);
#pragma unroll
  for (int b = 0; b < 16; ++b) s[b] = fmaf(mv[2], dreg[2][b], s[b]);
#pragma unroll
  for (int b = 0; b < 16; ++b) s[b] = fmaf(mv[3], dreg[3][b], s[b]);
#pragma unroll
  for (int q = 0; q < 4; ++q) {
    const float4 dc = *reinterpret_cast<const float4*>(&dc_lds[c][4 * q]);
    z[4 * q + 0] = fmaf(dc.x, s[4 * q + 0], z[4 * q + 0]);
    z[4 * q + 1] = fmaf(dc.y, s[4 * q + 1], z[4 * q + 1]);
    z[4 * q + 2] = fmaf(dc.z, s[4 * q + 2], z[4 * q + 2]);
    z[4 * q + 3] = fmaf(dc.w, s[4 * q + 3], z[4 * q + 3]);
  }
}

__global__ __launch_bounds__(256) void k_dist(const float* __restrict__ emb,
                                              const float* __restrict__ means,
                                              const float* __restrict__ icov,
                                              float* __restrict__ dist,
                                              unsigned int* __restrict__ mm) {
  __shared__ float dc_lds[NC][20];      // [c][b]+pad: broadcast reads (hot loop)
  __shared__ float db_lds[NB][NC + 8];  // [b][c]+pad: conflict-free dreg load
  __shared__ float zbuf[4][16];

  const int bid = blockIdx.x;
  const int p = (bid & 7) * (NP >> 3) + (bid >> 3);  // XCD swizzle (3136 % 8 == 0)
  const int t = threadIdx.x;
  const int lane = t & 63;
  const int wv = t >> 6;

  if (bid == 0 && t == 0) {  // init for k_blur (every call: graph-replay safe)
    mm[0] = 0x7f800000u;  // +inf
    mm[1] = 0u;           // 0 (scores nonneg)
    mm[2] = 0u;           // completion counter
  }

  // icov loads are NONTEMPORAL: each line is read by exactly one block (zero
  // reuse) — nt keeps the 822MB stream from thrashing L2/L3 so the emb gather
  // lines (16-block reuse) stay resident. Hoist the first 4 row loads above
  // the staging phase (no dependency) to hide staging under the stream fill.
  const float* mbase = icov + (size_t)p * (NC * NC) + (size_t)(wv * 64) * NC + 4 * lane;
#define LOADM(r) __builtin_nontemporal_load( \
    reinterpret_cast<const f4*>(mbase + (size_t)(r) * NC))

  f4 m0 = LOADM(0), m1 = LOADM(1), m2 = LOADM(2), m3 = LOADM(3);

  // stage delta[c][b] = emb[b][c][p] - means[p][c]; thread t owns c = t
  // (strided emb gather is L2/L3-served — R3 verified a coalescing pre-pass
  //  is pure overhead)
  {
    const int c = t;
    const float mn = means[(size_t)p * NC + c];
    const float* ep = emb + (size_t)c * NP + p;
    float d[16];
#pragma unroll
    for (int b = 0; b < 16; ++b) d[b] = ep[(size_t)b * (NC * NP)] - mn;
#pragma unroll
    for (int q = 0; q < 4; ++q) {
      *reinterpret_cast<float4*>(&dc_lds[c][4 * q]) =
          make_float4(d[4 * q], d[4 * q + 1], d[4 * q + 2], d[4 * q + 3]);
    }
#pragma unroll
    for (int b = 0; b < 16; ++b) db_lds[b][c] = d[b];
  }
  __syncthreads();

  float dreg[4][16];
#pragma unroll
  for (int b = 0; b < 16; ++b) {
    const float4 v = *reinterpret_cast<const float4*>(&db_lds[b][4 * lane]);
    dreg[0][b] = v.x; dreg[1][b] = v.y; dreg[2][b] = v.z; dreg[3][b] = v.w;
  }

  float z[16];
#pragma unroll
  for (int b = 0; b < 16; ++b) z[b] = 0.f;

  for (int rb = 0; rb < 64; rb += 4) {
    const int r4 = (rb + 4 < 64) ? rb + 4 : 63;
    const int r5 = (rb + 5 < 64) ? rb + 5 : 63;
    const int r6 = (rb + 6 < 64) ? rb + 6 : 63;
    const int r7 = (rb + 7 < 64) ? rb + 7 : 63;
    const f4 n0 = LOADM(r4);
    const f4 n1 = LOADM(r5);
    const f4 n2 = LOADM(r6);
    const f4 n3 = LOADM(r7);
    rowstep(m0, wv * 64 + rb + 0, dreg, z, dc_lds);
    rowstep(m1, wv * 64 + rb + 1, dreg, z, dc_lds);
    rowstep(m2, wv * 64 + rb + 2, dreg, z, dc_lds);
    rowstep(m3, wv * 64 + rb + 3, dreg, z, dc_lds);
    m0 = n0; m1 = n1; m2 = n2; m3 = n3;
  }
#undef LOADM

#pragma unroll
  for (int b = 0; b < 16; ++b) {
    float v = z[b];
#pragma unroll
    for (int off = 32; off > 0; off >>= 1) v += __shfl_xor(v, off, 64);
    z[b] = v;
  }
  if (lane == 0) {
#pragma unroll
    for (int b = 0; b < 16; ++b) zbuf[wv][b] = z[b];
  }
  __syncthreads();
  if (t < 16) {
    const float d2 = zbuf[0][t] + zbuf[1][t] + zbuf[2][t] + zbuf[3][t];
    dist[(size_t)t * NP + p] = sqrtf(d2);
  }
}

// ---------------- Stage 2: resize + blur + min/max + normalize (one kernel) --
// out = Cy * dist_b * Cx^T (composed bilinear+gaussian coefficients, <=13
// nonzeros/row, reflection & clamp folded in; unnormalized gaussian — the
// constant cancels in min-max normalization). 128 blocks: 16 images x 4
// column strips x 2 y-halves; each block keeps its 112x56 strip in LDS,
// contributes min/max via device atomics, spin-barrier rendezvous (128 blocks
// @ 54KB LDS -> 2/CU, all co-resident), then normalizes directly to output.
__global__ __launch_bounds__(256) void k_blur(const float* __restrict__ dist,
                                              float* __restrict__ out,
                                              unsigned int* __restrict__ mm) {
  __shared__ float w[33];
  __shared__ float ld[56 * 56];
  __shared__ float ccx[56][13];
  __shared__ float ccy[112][13];
  __shared__ int xlo[56];
  __shared__ int ylo[112];
  __shared__ float rbuf[33][57];      // u-window x strip cols
  __shared__ float sout[112][56];
  __shared__ float red[4][2];

  const int t = threadIdx.x;
  const int b = blockIdx.x >> 3;
  const int x0 = ((blockIdx.x >> 1) & 3) * 56;
  const int yh = blockIdx.x & 1;
  const int ybase = yh * 112;
  const int ubase = yh * 23;  // u-window start (ylo(112) = 23; window <= 33 rows)

  if (t < 33) {
    const float d = (float)(t - 16);
    w[t] = expf(-d * d * (1.f / 32.f));
  }
  for (int i = t; i < 56 * 56; i += 256) ld[i] = dist[(size_t)b * NP + i];
  __syncthreads();

  // build Cy rows for this y-half (one thread per output y)
  if (t < 112) {
    const int y = ybase + t;
    int lo = 56;
    for (int j = 0; j < 33; ++j) {
      int yy = y + j - 16;
      yy = (yy < 0) ? (-1 - yy) : (yy >= 224 ? 447 - yy : yy);
      const int U = (int)floorf(yy * 0.25f - 0.375f);
      const int u0c = U < 0 ? 0 : U;
      lo = lo < u0c ? lo : u0c;
    }
    ylo[t] = lo;
#pragma unroll
    for (int n = 0; n < 13; ++n) ccy[t][n] = 0.f;
    for (int j = 0; j < 33; ++j) {
      int yy = y + j - 16;
      yy = (yy < 0) ? (-1 - yy) : (yy >= 224 ? 447 - yy : yy);
      const float sy = yy * 0.25f - 0.375f;
      const int U = (int)floorf(sy);
      const float fy = sy - (float)U;
      const int u0c = U < 0 ? 0 : U;
      const int u1c = (U + 1) > 55 ? 55 : (U + 1);
      ccy[t][u0c - lo] += w[j] * (1.f - fy);
      ccy[t][u1c - lo] += w[j] * fy;
    }
  }
  // build Cx rows for this strip (one thread per strip column)
  if (t < 56) {
    const int x = x0 + t;
    int lo = 56;
    for (int j = 0; j < 33; ++j) {
      int xx = x + j - 16;
      xx = (xx < 0) ? (-1 - xx) : (xx >= 224 ? 447 - xx : xx);
      const int U = (int)floorf(xx * 0.25f - 0.375f);
      const int u0c = U < 0 ? 0 : U;
      lo = lo < u0c ? lo : u0c;
    }
    xlo[t] = lo;
#pragma unroll
    for (int n = 0; n < 13; ++n) ccx[t][n] = 0.f;
    for (int j = 0; j < 33; ++j) {
      int xx = x + j - 16;
      xx = (xx < 0) ? (-1 - xx) : (xx >= 224 ? 447 - xx : xx);
      const float sx = xx * 0.25f - 0.375f;
      const int U = (int)floorf(sx);
      const float fx = sx - (float)U;
      const int u0c = U < 0 ? 0 : U;
      const int u1c = (U + 1) > 55 ? 55 : (U + 1);
      ccx[t][u0c - lo] += w[j] * (1.f - fx);
      ccx[t][u1c - lo] += w[j] * fx;
    }
  }
  __syncthreads();

  // rbuf[u-ubase][lx] = sum_v Cx[lx][v] * ld[u][v]  (only the 33-row u-window)
  for (int i = t; i < 33 * 56; i += 256) {
    const int ur = i / 56, lx = i - 56 * ur;
    const int u = ubase + ur;
    const int lo = xlo[lx];
    const float* lrow = &ld[(u > 55 ? 55 : u) * 56];
    float acc = 0.f;
#pragma unroll
    for (int n = 0; n < 13; ++n) {
      int v = lo + n;
      v = v > 55 ? 55 : v;  // coeff is 0 there; clamp keeps the read in-tile
      acc = fmaf(ccx[lx][n], lrow[v], acc);
    }
    rbuf[ur][lx] = acc;
  }
  __syncthreads();

  // sout[yl][x] = sum_u Cy[yl][u] * rbuf[u][x]; 2 threads per row (28 cols each)
  float mnv = 1e30f, mxv = 0.f;
  if (t < 224) {
    const int yl = t >> 1;
    const int xh = (t & 1) * 28;
    const int lo = ylo[yl];
    for (int c = 0; c < 7; ++c) {
      float a0 = 0.f, a1 = 0.f, a2 = 0.f, a3 = 0.f;
#pragma unroll
      for (int n = 0; n < 13; ++n) {
        int ur = lo + n - ubase;
        ur = ur < 0 ? 0 : (ur > 32 ? 32 : ur);
        const float cy = ccy[yl][n];
        const float* rrow = &rbuf[ur][xh + c * 4];
        a0 = fmaf(cy, rrow[0], a0); a1 = fmaf(cy, rrow[1], a1);
        a2 = fmaf(cy, rrow[2], a2); a3 = fmaf(cy, rrow[3], a3);
      }
      float* srow = &sout[yl][xh + c * 4];
      srow[0] = a0; srow[1] = a1; srow[2] = a2; srow[3] = a3;
      mnv = fminf(mnv, fminf(fminf(a0, a1), fminf(a2, a3)));
      mxv = fmaxf(mxv, fmaxf(fmaxf(a0, a1), fmaxf(a2, a3)));
    }
  }
#pragma unroll
  for (int off = 32; off > 0; off >>= 1) {
    mnv = fminf(mnv, __shfl_xor(mnv, off, 64));
    mxv = fmaxf(mxv, __shfl_xor(mxv, off, 64));
  }
  const int lane = t & 63, wv = t >> 6;
  if (lane == 0) { red[wv][0] = mnv; red[wv][1] = mxv; }
  __syncthreads();

  if (t == 0) {
    const float m0 = fminf(fminf(red[0][0], red[1][0]), fminf(red[2][0], red[3][0]));
    const float m1 = fmaxf(fmaxf(red[0][1], red[1][1]), fmaxf(red[2][1], red[3][1]));
    atomicMin(&mm[0], __float_as_uint(m0));   // nonneg floats monotone as uints
    atomicMax(&mm[1], __float_as_uint(m1));
    __threadfence();
    atomicAdd(&mm[2], 1u);
    while (atomicAdd(&mm[2], 0u) < 128u) {  // spin: all 128 blocks co-resident
    }
    __threadfence();
    red[0][0] = __uint_as_float(atomicAdd(&mm[0], 0u));
    red[0][1] = __uint_as_float(atomicAdd(&mm[1], 0u));
  }
  __syncthreads();

  const float gmn = red[0][0];
  const float inv = 1.f / (red[0][1] - gmn);
  // normalized write: 112 rows x 14 float4 (x0 multiple of 56 -> 224B aligned)
  for (int i = t; i < 112 * 14; i += 256) {
    const int yl = i / 14, c = i - 14 * yl;
    const float* s = &sout[yl][c * 4];
    float4 v = make_float4((s[0] - gmn) * inv, (s[1] - gmn) * inv,
                           (s[2] - gmn) * inv, (s[3] - gmn) * inv);
    *reinterpret_cast<float4*>(out + ((size_t)b * OW + ybase + yl) * OW + x0 +
                               c * 4) = v;
  }
}

extern "C" void kernel_launch(void* const* d_in, const int* in_sizes, int n_in,
                              void* d_out, int out_size, void* d_ws, size_t ws_size,
                              hipStream_t stream) {
  const float* emb = (const float*)d_in[0];    // [16,256,3136]
  const float* means = (const float*)d_in[1];  // [3136,256]
  const float* icov = (const float*)d_in[2];   // [3136,256,256]
  float* out = (float*)d_out;                  // [16,224,224]

  char* ws = (char*)d_ws;
  float* dist = (float*)ws;                        // 16*3136 floats @ 0
  unsigned int* mm = (unsigned int*)(ws + 3416064);

  k_dist<<<NP, 256, 0, stream>>>(emb, means, icov, dist, mm);
  k_blur<<<NB * 8, 256, 0, stream>>>(dist, out, mm);
}

// Round 14
// 202.807 us; speedup vs baseline: 1.0404x; 1.0404x over previous
//
#include <hip/hip_runtime.h>
#include <math.h>

#define NP 3136
#define NC 256
#define NB 16
#define HH 56
#define OW 224

// ---------------- Stage 1: Mahalanobis distance (R2 version, measured best) --
__device__ __forceinline__ void rowstep(const float4 mv, const int c,
                                        const float (&dreg)[4][16], float (&z)[16],
                                        const float (*dc_lds)[20]) {
  float s[16];
#pragma unroll
  for (int b = 0; b < 16; ++b) s[b] = mv.x * dreg[0][b];
#pragma unroll
  for (int b = 0; b < 16; ++b) s[b] = fmaf(mv.y, dreg[1][b], s[b]);
#pragma unroll
  for (int b = 0; b < 16; ++b) s[b] = fmaf(mv.z, dreg[2][b], s[b]);
#pragma unroll
  for (int b = 0; b < 16; ++b) s[b] = fmaf(mv.w, dreg[3][b], s[b]);
#pragma unroll
  for (int q = 0; q < 4; ++q) {
    const float4 dc = *reinterpret_cast<const float4*>(&dc_lds[c][4 * q]);
    z[4 * q + 0] = fmaf(dc.x, s[4 * q + 0], z[4 * q + 0]);
    z[4 * q + 1] = fmaf(dc.y, s[4 * q + 1], z[4 * q + 1]);
    z[4 * q + 2] = fmaf(dc.z, s[4 * q + 2], z[4 * q + 2]);
    z[4 * q + 3] = fmaf(dc.w, s[4 * q + 3], z[4 * q + 3]);
  }
}

__global__ __launch_bounds__(256) void k_dist(const float* __restrict__ emb,
                                              const float* __restrict__ means,
                                              const float* __restrict__ icov,
                                              float* __restrict__ dist,
                                              unsigned int* __restrict__ mm) {
  __shared__ float dc_lds[NC][20];      // [c][b]+pad: broadcast reads (hot loop)
  __shared__ float db_lds[NB][NC + 8];  // [b][c]+pad: conflict-free dreg load
  __shared__ float zbuf[4][16];

  const int bid = blockIdx.x;
  const int p = (bid & 7) * (NP >> 3) + (bid >> 3);  // XCD swizzle (3136 % 8 == 0)
  const int t = threadIdx.x;
  const int lane = t & 63;
  const int wv = t >> 6;

  if (bid == 0 && t == 0) { mm[0] = 0x7f800000u; mm[1] = 0u; }  // init for k_blur

  {
    const int c = t;
    const float mn = means[(size_t)p * NC + c];
    const float* ep = emb + (size_t)c * NP + p;
    float d[16];
#pragma unroll
    for (int b = 0; b < 16; ++b) d[b] = ep[(size_t)b * (NC * NP)] - mn;
#pragma unroll
    for (int q = 0; q < 4; ++q) {
      *reinterpret_cast<float4*>(&dc_lds[c][4 * q]) =
          make_float4(d[4 * q], d[4 * q + 1], d[4 * q + 2], d[4 * q + 3]);
    }
#pragma unroll
    for (int b = 0; b < 16; ++b) db_lds[b][c] = d[b];
  }
  __syncthreads();

  float dreg[4][16];
#pragma unroll
  for (int b = 0; b < 16; ++b) {
    const float4 v = *reinterpret_cast<const float4*>(&db_lds[b][4 * lane]);
    dreg[0][b] = v.x; dreg[1][b] = v.y; dreg[2][b] = v.z; dreg[3][b] = v.w;
  }

  float z[16];
#pragma unroll
  for (int b = 0; b < 16; ++b) z[b] = 0.f;

  const float* mbase = icov + (size_t)p * (NC * NC) + (size_t)(wv * 64) * NC + 4 * lane;
#define LOADM(r) (*reinterpret_cast<const float4*>(mbase + (size_t)(r) * NC))

  float4 m0 = LOADM(0), m1 = LOADM(1), m2 = LOADM(2), m3 = LOADM(3);
  for (int rb = 0; rb < 64; rb += 4) {
    const int r4 = (rb + 4 < 64) ? rb + 4 : 63;
    const int r5 = (rb + 5 < 64) ? rb + 5 : 63;
    const int r6 = (rb + 6 < 64) ? rb + 6 : 63;
    const int r7 = (rb + 7 < 64) ? rb + 7 : 63;
    const float4 n0 = LOADM(r4);
    const float4 n1 = LOADM(r5);
    const float4 n2 = LOADM(r6);
    const float4 n3 = LOADM(r7);
    rowstep(m0, wv * 64 + rb + 0, dreg, z, dc_lds);
    rowstep(m1, wv * 64 + rb + 1, dreg, z, dc_lds);
    rowstep(m2, wv * 64 + rb + 2, dreg, z, dc_lds);
    rowstep(m3, wv * 64 + rb + 3, dreg, z, dc_lds);
    m0 = n0; m1 = n1; m2 = n2; m3 = n3;
  }
#undef LOADM

#pragma unroll
  for (int b = 0; b < 16; ++b) {
    float v = z[b];
#pragma unroll
    for (int off = 32; off > 0; off >>= 1) v += __shfl_xor(v, off, 64);
    z[b] = v;
  }
  if (lane == 0) {
#pragma unroll
    for (int b = 0; b < 16; ++b) zbuf[wv][b] = z[b];
  }
  __syncthreads();
  if (t < 16) {
    const float d2 = zbuf[0][t] + zbuf[1][t] + zbuf[2][t] + zbuf[3][t];
    dist[(size_t)t * NP + p] = sqrtf(d2);
  }
}

// ---------------- Stage 2: fused resize + row/col gaussian + min/max ---------
// out = Cy * dist_b * Cx^T (composed bilinear+gaussian coefficient matrices,
// <=13 nonzeros/row, reflection & clamp folded in; unnormalized gaussian — the
// constant cancels in min-max normalization). Grid: 16 images x 4 strips.
// VECTORIZED (R14): rb padded to stride 60 so the y-pass reads it as aligned
// float4 (13 ds_read_b128/chunk instead of 52 ds_read_b32) and writes float4
// global stores — the y-pass was LDS-instruction-bound (728 scalar reads/thread).
__global__ __launch_bounds__(256) void k_blur(const float* __restrict__ dist,
                                              float* __restrict__ outb,
                                              unsigned int* __restrict__ mm) {
  __shared__ float w[33];
  __shared__ float ld[56 * 56];       // source image tile
  __shared__ float ccx[56][13];       // x-composed coeffs for this strip
  __shared__ float ccy[224][13];      // y-composed coeffs
  __shared__ int xlo[56];
  __shared__ int ylo[224];
  __shared__ float rb[56][60];        // ld * Cx^T; stride 60 -> aligned float4
  __shared__ float red[4][2];

  const int t = threadIdx.x;
  const int b = blockIdx.x >> 2;
  const int x0 = (blockIdx.x & 3) * 56;

  if (t < 33) {
    const float d = (float)(t - 16);
    w[t] = expf(-d * d * (1.f / 32.f));
  }
  // vectorized tile load: 3136 floats = 784 float4 (dist image base 16B-aligned)
  {
    const float4* src = reinterpret_cast<const float4*>(dist + (size_t)b * NP);
    float4* dst = reinterpret_cast<float4*>(ld);
    for (int i = t; i < 784; i += 256) dst[i] = src[i];
  }
  __syncthreads();

  // build Cy rows (one thread per output y)
  if (t < 224) {
    const int y = t;
    int lo = 56;
    for (int j = 0; j < 33; ++j) {
      int yy = y + j - 16;
      yy = (yy < 0) ? (-1 - yy) : (yy >= 224 ? 447 - yy : yy);
      const int U = (int)floorf(yy * 0.25f - 0.375f);
      const int u0c = U < 0 ? 0 : U;
      lo = lo < u0c ? lo : u0c;
    }
    ylo[y] = lo;
#pragma unroll
    for (int n = 0; n < 13; ++n) ccy[y][n] = 0.f;
    for (int j = 0; j < 33; ++j) {
      int yy = y + j - 16;
      yy = (yy < 0) ? (-1 - yy) : (yy >= 224 ? 447 - yy : yy);
      const float sy = yy * 0.25f - 0.375f;
      const int U = (int)floorf(sy);
      const float fy = sy - (float)U;
      const int u0c = U < 0 ? 0 : U;
      const int u1c = (U + 1) > 55 ? 55 : (U + 1);
      ccy[y][u0c - lo] += w[j] * (1.f - fy);
      ccy[y][u1c - lo] += w[j] * fy;
    }
  }
  // build Cx rows for this strip (one thread per strip column)
  if (t < 56) {
    const int x = x0 + t;
    int lo = 56;
    for (int j = 0; j < 33; ++j) {
      int xx = x + j - 16;
      xx = (xx < 0) ? (-1 - xx) : (xx >= 224 ? 447 - xx : xx);
      const int U = (int)floorf(xx * 0.25f - 0.375f);
      const int u0c = U < 0 ? 0 : U;
      lo = lo < u0c ? lo : u0c;
    }
    xlo[t] = lo;
#pragma unroll
    for (int n = 0; n < 13; ++n) ccx[t][n] = 0.f;
    for (int j = 0; j < 33; ++j) {
      int xx = x + j - 16;
      xx = (xx < 0) ? (-1 - xx) : (xx >= 224 ? 447 - xx : xx);
      const float sx = xx * 0.25f - 0.375f;
      const int U = (int)floorf(sx);
      const float fx = sx - (float)U;
      const int u0c = U < 0 ? 0 : U;
      const int u1c = (U + 1) > 55 ? 55 : (U + 1);
      ccx[t][u0c - lo] += w[j] * (1.f - fx);
      ccx[t][u1c - lo] += w[j] * fx;
    }
  }
  __syncthreads();

  // rb[u][lx] = sum_v Cx[lx][v] * ld[u][v]
  for (int i = t; i < 56 * 56; i += 256) {
    const int u = i / 56, lx = i - 56 * u;
    const int lo = xlo[lx];
    const float* lrow = &ld[u * 56];
    float acc = 0.f;
#pragma unroll
    for (int n = 0; n < 13; ++n) {
      int v = lo + n;
      v = v > 55 ? 55 : v;  // coeff is 0 there; clamp keeps the read in-tile
      acc = fmaf(ccx[lx][n], lrow[v], acc);
    }
    rb[u][lx] = acc;
  }
  __syncthreads();

  // out[y][x0+..] = sum_u Cy[y][u] * rb[u][..]; float4 LDS reads + stores
  float mnv = 1e30f, mxv = 0.f;
  if (t < 224) {
    const int y = t;
    const int lo = ylo[y];
    float* orow = outb + ((size_t)b * OW + y) * OW + x0;
    for (int c = 0; c < 14; ++c) {
      float ax = 0.f, ay = 0.f, az = 0.f, aw = 0.f;
#pragma unroll
      for (int n = 0; n < 13; ++n) {
        int u = lo + n;
        u = u > 55 ? 55 : u;
        const float cy = ccy[y][n];
        const float4 rv = *reinterpret_cast<const float4*>(&rb[u][c * 4]);
        ax = fmaf(cy, rv.x, ax); ay = fmaf(cy, rv.y, ay);
        az = fmaf(cy, rv.z, az); aw = fmaf(cy, rv.w, aw);
      }
      *reinterpret_cast<float4*>(orow + c * 4) = make_float4(ax, ay, az, aw);
      mnv = fminf(mnv, fminf(fminf(ax, ay), fminf(az, aw)));
      mxv = fmaxf(mxv, fmaxf(fmaxf(ax, ay), fmaxf(az, aw)));
    }
  }
#pragma unroll
  for (int off = 32; off > 0; off >>= 1) {
    mnv = fminf(mnv, __shfl_xor(mnv, off, 64));
    mxv = fmaxf(mxv, __shfl_xor(mxv, off, 64));
  }
  const int lane = t & 63, wv = t >> 6;
  if (lane == 0) { red[wv][0] = mnv; red[wv][1] = mxv; }
  __syncthreads();
  if (t == 0) {
    const float m0 = fminf(fminf(red[0][0], red[1][0]), fminf(red[2][0], red[3][0]));
    const float m1 = fmaxf(fmaxf(red[0][1], red[1][1]), fmaxf(red[2][1], red[3][1]));
    atomicMin(&mm[0], __float_as_uint(m0));   // nonneg floats monotone as uints
    atomicMax(&mm[1], __float_as_uint(m1));
  }
}

// ---------------- Stage 2c: normalize (float4) ----------------
__global__ __launch_bounds__(256) void k_norm(const float4* __restrict__ in,
                                              const unsigned int* __restrict__ mm,
                                              float4* __restrict__ out) {
  const int i = blockIdx.x * 256 + threadIdx.x;  // 200704 float4s exactly
  const float mn = __uint_as_float(mm[0]);
  const float mx = __uint_as_float(mm[1]);
  const float inv = 1.f / (mx - mn);
  const float4 v = in[i];
  out[i] = make_float4((v.x - mn) * inv, (v.y - mn) * inv,
                       (v.z - mn) * inv, (v.w - mn) * inv);
}

extern "C" void kernel_launch(void* const* d_in, const int* in_sizes, int n_in,
                              void* d_out, int out_size, void* d_ws, size_t ws_size,
                              hipStream_t stream) {
  const float* emb = (const float*)d_in[0];    // [16,256,3136]
  const float* means = (const float*)d_in[1];  // [3136,256]
  const float* icov = (const float*)d_in[2];   // [3136,256,256]
  float* out = (float*)d_out;                  // [16,224,224]

  char* ws = (char*)d_ws;
  float* dist = (float*)ws;                        // 16*3136 floats @ 0
  float* tmp1 = (float*)(ws + 204800);             // 16*224*224 floats
  unsigned int* mm = (unsigned int*)(ws + 3416064);

  k_dist<<<NP, 256, 0, stream>>>(emb, means, icov, dist, mm);
  k_blur<<<NB * 4, 256, 0, stream>>>(dist, tmp1, mm);
  k_norm<<<NB * OW * OW / 1024, 256, 0, stream>>>((const float4*)tmp1, mm,
                                                  (float4*)out);
}

// Round 15
// 201.789 us; speedup vs baseline: 1.0456x; 1.0050x over previous
//
#include <hip/hip_runtime.h>
#include <math.h>

#define NP 3136
#define NC 256
#define NB 16
#define HH 56
#define OW 224

// ---------------- Stage 1: Mahalanobis distance (R2 version, measured best) --
__device__ __forceinline__ void rowstep(const float4 mv, const int c,
                                        const float (&dreg)[4][16], float (&z)[16],
                                        const float (*dc_lds)[20]) {
  float s[16];
#pragma unroll
  for (int b = 0; b < 16; ++b) s[b] = mv.x * dreg[0][b];
#pragma unroll
  for (int b = 0; b < 16; ++b) s[b] = fmaf(mv.y, dreg[1][b], s[b]);
#pragma unroll
  for (int b = 0; b < 16; ++b) s[b] = fmaf(mv.z, dreg[2][b], s[b]);
#pragma unroll
  for (int b = 0; b < 16; ++b) s[b] = fmaf(mv.w, dreg[3][b], s[b]);
#pragma unroll
  for (int q = 0; q < 4; ++q) {
    const float4 dc = *reinterpret_cast<const float4*>(&dc_lds[c][4 * q]);
    z[4 * q + 0] = fmaf(dc.x, s[4 * q + 0], z[4 * q + 0]);
    z[4 * q + 1] = fmaf(dc.y, s[4 * q + 1], z[4 * q + 1]);
    z[4 * q + 2] = fmaf(dc.z, s[4 * q + 2], z[4 * q + 2]);
    z[4 * q + 3] = fmaf(dc.w, s[4 * q + 3], z[4 * q + 3]);
  }
}

__global__ __launch_bounds__(256) void k_dist(const float* __restrict__ emb,
                                              const float* __restrict__ means,
                                              const float* __restrict__ icov,
                                              float* __restrict__ dist,
                                              unsigned int* __restrict__ mm) {
  __shared__ float dc_lds[NC][20];      // [c][b]+pad: broadcast reads (hot loop)
  __shared__ float db_lds[NB][NC + 8];  // [b][c]+pad: conflict-free dreg load
  __shared__ float zbuf[4][16];

  const int bid = blockIdx.x;
  const int p = (bid & 7) * (NP >> 3) + (bid >> 3);  // XCD swizzle (3136 % 8 == 0)
  const int t = threadIdx.x;
  const int lane = t & 63;
  const int wv = t >> 6;

  if (bid == 0 && t == 0) { mm[0] = 0x7f800000u; mm[1] = 0u; }  // init for k_blur

  {
    const int c = t;
    const float mn = means[(size_t)p * NC + c];
    const float* ep = emb + (size_t)c * NP + p;
    float d[16];
#pragma unroll
    for (int b = 0; b < 16; ++b) d[b] = ep[(size_t)b * (NC * NP)] - mn;
#pragma unroll
    for (int q = 0; q < 4; ++q) {
      *reinterpret_cast<float4*>(&dc_lds[c][4 * q]) =
          make_float4(d[4 * q], d[4 * q + 1], d[4 * q + 2], d[4 * q + 3]);
    }
#pragma unroll
    for (int b = 0; b < 16; ++b) db_lds[b][c] = d[b];
  }
  __syncthreads();

  float dreg[4][16];
#pragma unroll
  for (int b = 0; b < 16; ++b) {
    const float4 v = *reinterpret_cast<const float4*>(&db_lds[b][4 * lane]);
    dreg[0][b] = v.x; dreg[1][b] = v.y; dreg[2][b] = v.z; dreg[3][b] = v.w;
  }

  float z[16];
#pragma unroll
  for (int b = 0; b < 16; ++b) z[b] = 0.f;

  const float* mbase = icov + (size_t)p * (NC * NC) + (size_t)(wv * 64) * NC + 4 * lane;
#define LOADM(r) (*reinterpret_cast<const float4*>(mbase + (size_t)(r) * NC))

  float4 m0 = LOADM(0), m1 = LOADM(1), m2 = LOADM(2), m3 = LOADM(3);
  for (int rb = 0; rb < 64; rb += 4) {
    const int r4 = (rb + 4 < 64) ? rb + 4 : 63;
    const int r5 = (rb + 5 < 64) ? rb + 5 : 63;
    const int r6 = (rb + 6 < 64) ? rb + 6 : 63;
    const int r7 = (rb + 7 < 64) ? rb + 7 : 63;
    const float4 n0 = LOADM(r4);
    const float4 n1 = LOADM(r5);
    const float4 n2 = LOADM(r6);
    const float4 n3 = LOADM(r7);
    rowstep(m0, wv * 64 + rb + 0, dreg, z, dc_lds);
    rowstep(m1, wv * 64 + rb + 1, dreg, z, dc_lds);
    rowstep(m2, wv * 64 + rb + 2, dreg, z, dc_lds);
    rowstep(m3, wv * 64 + rb + 3, dreg, z, dc_lds);
    m0 = n0; m1 = n1; m2 = n2; m3 = n3;
  }
#undef LOADM

#pragma unroll
  for (int b = 0; b < 16; ++b) {
    float v = z[b];
#pragma unroll
    for (int off = 32; off > 0; off >>= 1) v += __shfl_xor(v, off, 64);
    z[b] = v;
  }
  if (lane == 0) {
#pragma unroll
    for (int b = 0; b < 16; ++b) zbuf[wv][b] = z[b];
  }
  __syncthreads();
  if (t < 16) {
    const float d2 = zbuf[0][t] + zbuf[1][t] + zbuf[2][t] + zbuf[3][t];
    dist[(size_t)t * NP + p] = sqrtf(d2);
  }
}

// ---------------- Stage 2: fused resize + row/col gaussian + min/max ---------
// out = Cy * dist_b * Cx^T (composed bilinear+gaussian coefficient matrices,
// <=13 nonzeros/row, reflection & clamp folded in; unnormalized gaussian — the
// constant cancels in min-max normalization).
// R15: regrid 64 -> 224 blocks (16 images x 14 strips of 16 cols) so k_blur
// uses ~all CUs instead of 64; rb stride 20 (float4-aligned, u*20 mod 32
// cycles 8 offsets -> no 8-way y-pass bank conflict).
__global__ __launch_bounds__(256) void k_blur(const float* __restrict__ dist,
                                              float* __restrict__ outb,
                                              unsigned int* __restrict__ mm) {
  __shared__ float w[33];
  __shared__ float ld[56 * 56];       // source image tile
  __shared__ float ccx[16][13];       // x-composed coeffs for this strip
  __shared__ float ccy[224][13];      // y-composed coeffs
  __shared__ int xlo[16];
  __shared__ int ylo[224];
  __shared__ float rb[56][20];        // ld * Cx^T; stride 20 -> aligned float4
  __shared__ float red[4][2];

  const int t = threadIdx.x;
  const int b = blockIdx.x / 14;
  const int x0 = (blockIdx.x % 14) * 16;

  if (t < 33) {
    const float d = (float)(t - 16);
    w[t] = expf(-d * d * (1.f / 32.f));
  }
  // vectorized tile load: 3136 floats = 784 float4 (dist image base 16B-aligned)
  {
    const float4* src = reinterpret_cast<const float4*>(dist + (size_t)b * NP);
    float4* dst = reinterpret_cast<float4*>(ld);
    for (int i = t; i < 784; i += 256) dst[i] = src[i];
  }
  __syncthreads();

  // build Cy rows (one thread per output y)
  if (t < 224) {
    const int y = t;
    int lo = 56;
    for (int j = 0; j < 33; ++j) {
      int yy = y + j - 16;
      yy = (yy < 0) ? (-1 - yy) : (yy >= 224 ? 447 - yy : yy);
      const int U = (int)floorf(yy * 0.25f - 0.375f);
      const int u0c = U < 0 ? 0 : U;
      lo = lo < u0c ? lo : u0c;
    }
    ylo[y] = lo;
#pragma unroll
    for (int n = 0; n < 13; ++n) ccy[y][n] = 0.f;
    for (int j = 0; j < 33; ++j) {
      int yy = y + j - 16;
      yy = (yy < 0) ? (-1 - yy) : (yy >= 224 ? 447 - yy : yy);
      const float sy = yy * 0.25f - 0.375f;
      const int U = (int)floorf(sy);
      const float fy = sy - (float)U;
      const int u0c = U < 0 ? 0 : U;
      const int u1c = (U + 1) > 55 ? 55 : (U + 1);
      ccy[y][u0c - lo] += w[j] * (1.f - fy);
      ccy[y][u1c - lo] += w[j] * fy;
    }
  }
  // build Cx rows for this strip (one thread per strip column)
  if (t < 16) {
    const int x = x0 + t;
    int lo = 56;
    for (int j = 0; j < 33; ++j) {
      int xx = x + j - 16;
      xx = (xx < 0) ? (-1 - xx) : (xx >= 224 ? 447 - xx : xx);
      const int U = (int)floorf(xx * 0.25f - 0.375f);
      const int u0c = U < 0 ? 0 : U;
      lo = lo < u0c ? lo : u0c;
    }
    xlo[t] = lo;
#pragma unroll
    for (int n = 0; n < 13; ++n) ccx[t][n] = 0.f;
    for (int j = 0; j < 33; ++j) {
      int xx = x + j - 16;
      xx = (xx < 0) ? (-1 - xx) : (xx >= 224 ? 447 - xx : xx);
      const float sx = xx * 0.25f - 0.375f;
      const int U = (int)floorf(sx);
      const float fx = sx - (float)U;
      const int u0c = U < 0 ? 0 : U;
      const int u1c = (U + 1) > 55 ? 55 : (U + 1);
      ccx[t][u0c - lo] += w[j] * (1.f - fx);
      ccx[t][u1c - lo] += w[j] * fx;
    }
  }
  __syncthreads();

  // rb[u][lx] = sum_v Cx[lx][v] * ld[u][v]   (56 rows x 16 strip cols)
  for (int i = t; i < 56 * 16; i += 256) {
    const int u = i >> 4, lx = i & 15;
    const int lo = xlo[lx];
    const float* lrow = &ld[u * 56];
    float acc = 0.f;
#pragma unroll
    for (int n = 0; n < 13; ++n) {
      int v = lo + n;
      v = v > 55 ? 55 : v;  // coeff is 0 there; clamp keeps the read in-tile
      acc = fmaf(ccx[lx][n], lrow[v], acc);
    }
    rb[u][lx] = acc;
  }
  __syncthreads();

  // out[y][x0+..] = sum_u Cy[y][u] * rb[u][..]; 4 float4 chunks per row
  float mnv = 1e30f, mxv = 0.f;
  if (t < 224) {
    const int y = t;
    const int lo = ylo[y];
    float* orow = outb + ((size_t)b * OW + y) * OW + x0;
#pragma unroll
    for (int c = 0; c < 4; ++c) {
      float ax = 0.f, ay = 0.f, az = 0.f, aw = 0.f;
#pragma unroll
      for (int n = 0; n < 13; ++n) {
        int u = lo + n;
        u = u > 55 ? 55 : u;
        const float cy = ccy[y][n];
        const float4 rv = *reinterpret_cast<const float4*>(&rb[u][c * 4]);
        ax = fmaf(cy, rv.x, ax); ay = fmaf(cy, rv.y, ay);
        az = fmaf(cy, rv.z, az); aw = fmaf(cy, rv.w, aw);
      }
      *reinterpret_cast<float4*>(orow + c * 4) = make_float4(ax, ay, az, aw);
      mnv = fminf(mnv, fminf(fminf(ax, ay), fminf(az, aw)));
      mxv = fmaxf(mxv, fmaxf(fmaxf(ax, ay), fmaxf(az, aw)));
    }
  }
#pragma unroll
  for (int off = 32; off > 0; off >>= 1) {
    mnv = fminf(mnv, __shfl_xor(mnv, off, 64));
    mxv = fmaxf(mxv, __shfl_xor(mxv, off, 64));
  }
  const int lane = t & 63, wv = t >> 6;
  if (lane == 0) { red[wv][0] = mnv; red[wv][1] = mxv; }
  __syncthreads();
  if (t == 0) {
    const float m0 = fminf(fminf(red[0][0], red[1][0]), fminf(red[2][0], red[3][0]));
    const float m1 = fmaxf(fmaxf(red[0][1], red[1][1]), fmaxf(red[2][1], red[3][1]));
    atomicMin(&mm[0], __float_as_uint(m0));   // nonneg floats monotone as uints
    atomicMax(&mm[1], __float_as_uint(m1));
  }
}

// ---------------- Stage 2c: normalize (float4) ----------------
__global__ __launch_bounds__(256) void k_norm(const float4* __restrict__ in,
                                              const unsigned int* __restrict__ mm,
                                              float4* __restrict__ out) {
  const int i = blockIdx.x * 256 + threadIdx.x;  // 200704 float4s exactly
  const float mn = __uint_as_float(mm[0]);
  const float mx = __uint_as_float(mm[1]);
  const float inv = 1.f / (mx - mn);
  const float4 v = in[i];
  out[i] = make_float4((v.x - mn) * inv, (v.y - mn) * inv,
                       (v.z - mn) * inv, (v.w - mn) * inv);
}

extern "C" void kernel_launch(void* const* d_in, const int* in_sizes, int n_in,
                              void* d_out, int out_size, void* d_ws, size_t ws_size,
                              hipStream_t stream) {
  const float* emb = (const float*)d_in[0];    // [16,256,3136]
  const float* means = (const float*)d_in[1];  // [3136,256]
  const float* icov = (const float*)d_in[2];   // [3136,256,256]
  float* out = (float*)d_out;                  // [16,224,224]

  char* ws = (char*)d_ws;
  float* dist = (float*)ws;                        // 16*3136 floats @ 0
  float* tmp1 = (float*)(ws + 204800);             // 16*224*224 floats
  unsigned int* mm = (unsigned int*)(ws + 3416064);

  k_dist<<<NP, 256, 0, stream>>>(emb, means, icov, dist, mm);
  k_blur<<<NB * 14, 256, 0, stream>>>(dist, tmp1, mm);
  k_norm<<<NB * OW * OW / 1024, 256, 0, stream>>>((const float4*)tmp1, mm,
                                                  (float4*)out);
}